// Round 11
// baseline (267.519 us; speedup 1.0000x reference)
//
#include <hip/hip_runtime.h>

#define S_LEN 2048
#define NH 16
#define HDIM 128
#define DMODEL 2048

typedef __attribute__((ext_vector_type(8))) short bf16x8;
typedef __attribute__((ext_vector_type(4))) float f32x4;

using gas_cvp = const __attribute__((address_space(1))) void*;
using las_vp  = __attribute__((address_space(3))) void*;

__device__ __forceinline__ unsigned short f2bf(float x) {
  unsigned int u = __builtin_bit_cast(unsigned int, x);
  u += 0x7FFFu + ((u >> 16) & 1u);
  return (unsigned short)(u >> 16);
}
__device__ __forceinline__ float bf2f(unsigned short u) {
  unsigned int x = ((unsigned int)u) << 16;
  return __builtin_bit_cast(float, x);
}
__device__ __forceinline__ unsigned int cvt_pk_bf16(float lo, float hi) {
  unsigned int r;
  asm("v_cvt_pk_bf16_f32 %0, %1, %2" : "=v"(r) : "v"(lo), "v"(hi));
  return r;
}

// ---------- fp32 -> bf16 convert, both inputs in one dispatch ----------
__global__ __launch_bounds__(256) void cvt2_kernel(const float4* __restrict__ inq,
                                                   const float4* __restrict__ inkv,
                                                   ushort4* __restrict__ outq,
                                                   ushort4* __restrict__ outkv, int n4) {
  const float4* in = blockIdx.z ? inkv : inq;
  ushort4* out = blockIdx.z ? outkv : outq;
  int i = blockIdx.x * 256 + threadIdx.x;
  if (i < n4) {
    float4 v = in[i];
    ushort4 r;
    r.x = f2bf(v.x); r.y = f2bf(v.y); r.z = f2bf(v.z); r.w = f2bf(v.w);
    out[i] = r;
  }
}

// ---------- sin/cos table ----------
__global__ __launch_bounds__(256) void sincos_kernel(float2* __restrict__ sc) {
  int i = blockIdx.x * 256 + threadIdx.x;
  int s = i >> 6, j = i & 63;
  float inv_ts = 1.0f / powf(10000.0f, (float)j * (1.0f / 64.0f));
  float ang = (float)s * inv_ts;
  sc[i] = make_float2(sinf(ang), cosf(ang));
}

// ---------- RoPE (+scale), z=0: Q (scaled by 1/sqrt(HD)*log2e), z=1: K ----------
__global__ __launch_bounds__(256) void rope8_kernel(const unsigned short* __restrict__ XQ,
                                                    const unsigned short* __restrict__ XK,
                                                    const float2* __restrict__ sc,
                                                    unsigned short* __restrict__ outQ,
                                                    unsigned short* __restrict__ outK,
                                                    float qscale) {
  const unsigned short* X = blockIdx.z ? XK : XQ;
  unsigned short* out = blockIdx.z ? outK : outQ;
  float scale = blockIdx.z ? 1.0f : qscale;
  int i = blockIdx.x * 256 + threadIdx.x;   // [4096][16][8]
  int m = i >> 7;
  int r = i & 127;
  int h = r >> 3, jb = (r & 7) * 8;
  int s = m & (S_LEN - 1);
  size_t base = (size_t)m * DMODEL + h * HDIM + jb;
  int4 x1 = *(const int4*)(X + base);
  int4 x2 = *(const int4*)(X + base + 64);
  const float2* pp = sc + s * 64 + jb;
  int4 o1, o2;
  int* x1w = (int*)&x1; int* x2w = (int*)&x2;
  int* o1w = (int*)&o1; int* o2w = (int*)&o2;
#pragma unroll
  for (int w = 0; w < 4; w++) {
    float a_lo = bf2f((unsigned short)(x1w[w] & 0xffff));
    float a_hi = bf2f((unsigned short)((unsigned int)x1w[w] >> 16));
    float b_lo = bf2f((unsigned short)(x2w[w] & 0xffff));
    float b_hi = bf2f((unsigned short)((unsigned int)x2w[w] >> 16));
    float2 c0 = pp[w * 2], c1 = pp[w * 2 + 1];
    float r1l = (a_lo * c0.y - b_lo * c0.x) * scale;
    float r1h = (a_hi * c1.y - b_hi * c1.x) * scale;
    float r2l = (b_lo * c0.y + a_lo * c0.x) * scale;
    float r2h = (b_hi * c1.y + a_hi * c1.x) * scale;
    o1w[w] = (int)(cvt_pk_bf16(r1l, r1h));
    o2w[w] = (int)(cvt_pk_bf16(r2l, r2h));
  }
  *(int4*)(out + base) = o1;
  *(int4*)(out + base + 64) = o2;
}

// ---------- 2048x2048 weight transpose + convert, 4 weights ----------
__global__ __launch_bounds__(256) void wtrans4_kernel(const float* __restrict__ w0,
                                                      const float* __restrict__ w1,
                                                      const float* __restrict__ w2,
                                                      const float* __restrict__ w3,
                                                      unsigned short* __restrict__ outb) {
  __shared__ float tile[64][65];
  int z = blockIdx.z;
  const float* in = (z == 0) ? w0 : (z == 1) ? w1 : (z == 2) ? w2 : w3;
  unsigned short* out = outb + (size_t)z * DMODEL * DMODEL;
  int c0 = blockIdx.x * 64, r0 = blockIdx.y * 64;
  int tx = threadIdx.x & 63, ty = threadIdx.x >> 6;
#pragma unroll
  for (int i = 0; i < 16; i++) {
    int r = ty + i * 4;
    tile[r][tx] = in[(size_t)(r0 + r) * DMODEL + c0 + tx];
  }
  __syncthreads();
#pragma unroll
  for (int i = 0; i < 16; i++) {
    int c = ty + i * 4;
    out[(size_t)(c0 + c) * DMODEL + r0 + tx] = f2bf(tile[tx][c]);
  }
}

// ---------- V transpose: [B,S,H,HD] bf16 -> [B,H,HD,S] bf16 ----------
__global__ __launch_bounds__(256) void vtrans_kernel(const unsigned short* __restrict__ vf,
                                                     unsigned short* __restrict__ Vt) {
  __shared__ unsigned short tile[64][65];
  int z = blockIdx.z; int b = z >> 4, h = z & 15;
  const unsigned short* I = vf + (size_t)b * S_LEN * DMODEL + h * HDIM;
  unsigned short* O = Vt + (size_t)z * HDIM * S_LEN;
  int s0 = blockIdx.y * 64, f0 = blockIdx.x * 64;
  int tx = threadIdx.x & 63, ty = threadIdx.x >> 6;
#pragma unroll
  for (int i = 0; i < 16; i++) {
    int r = ty + i * 4;
    tile[r][tx] = I[(size_t)(s0 + r) * DMODEL + f0 + tx];
  }
  __syncthreads();
#pragma unroll
  for (int i = 0; i < 16; i++) {
    int c = ty + i * 4;
    O[(size_t)(f0 + c) * S_LEN + s0 + tx] = tile[tx][c];
  }
}

// ---------- 256x256 bf16 GEMM, octet pipeline, 1 barrier / K-tile ----------
__global__ __launch_bounds__(512, 1) void gemm256o_kernel(
    const unsigned short* __restrict__ Aq,
    const unsigned short* __restrict__ Akv,
    const unsigned short* __restrict__ W,    // [z][N][K]
    unsigned short* __restrict__ Cb) {       // [z][M][N] bf16
  constexpr int M = 4096, N = 2048, K = 2048, NT = K / 64;
  __shared__ char lds[131072];
  int wid = blockIdx.z * 128 + blockIdx.y * 8 + blockIdx.x;
  int nid = (wid & 7) * 32 + (wid >> 3);
  int z = nid >> 7;
  int rem = nid & 127;
  int bm = (rem >> 3) * 256, bn = (rem & 7) * 256;
  const unsigned short* A = (z == 0) ? Aq : Akv;
  const unsigned short* Bt = W + (size_t)z * N * K;

  int tid = threadIdx.x, wave = tid >> 6, lane = tid & 63;
  int lr = lane & 15, lq = lane >> 4;
  int wr = wave >> 2, wc = wave & 3;

  auto STAGE_P = [&](int t, int buf, int isB) {
    int k0 = t * 64;
    const unsigned short* src = isB ? Bt : A;
    int rbase = isB ? bn : bm;
    char* dst0 = lds + buf * 65536 + isB * 32768;
#pragma unroll
    for (int i = 0; i < 4; i++) {
      int o = i * 8192 + tid * 16;
      int row = o >> 7, colb = o & 127;
      int sc = colb ^ ((row & 7) << 4);
      __builtin_amdgcn_global_load_lds(
          (gas_cvp)(src + (size_t)(rbase + row) * K + k0 + (sc >> 1)),
          (las_vp)(dst0 + i * 8192 + wave * 1024), 16, 0, 0);
    }
  };
  auto LDA1 = [&](int buf, int m, int kk) -> bf16x8 {
    int row = wr * 128 + m * 16 + lr;
    return *(const bf16x8*)(lds + buf * 65536 + row * 128 +
                            (((kk * 4 + lq) ^ (row & 7)) << 4));
  };
  auto LDB1 = [&](int buf, int n, int kk) -> bf16x8 {
    int row = wc * 64 + n * 16 + lr;
    return *(const bf16x8*)(lds + buf * 65536 + 32768 + row * 128 +
                            (((kk * 4 + lq) ^ (row & 7)) << 4));
  };

  f32x4 acc[8][4] = {};
  bf16x8 aA[4][2], bB[4][2];

  auto OCT = [&](int P, int Q, int sb) {
#pragma unroll
    for (int kk = 0; kk < 2; kk++)
#pragma unroll
      for (int s = 0; s < 2; s++)
#pragma unroll
        for (int nn = 0; nn < 2; nn++)
          acc[2 * P + s][2 * Q + nn] = __builtin_amdgcn_mfma_f32_16x16x32_bf16(
              aA[sb + s][kk], bB[2 * Q + nn][kk], acc[2 * P + s][2 * Q + nn], 0, 0, 0);
  };
  auto RD_A2 = [&](int buf, int m0, int sb) {
#pragma unroll
    for (int kk = 0; kk < 2; kk++)
#pragma unroll
      for (int s = 0; s < 2; s++) aA[sb + s][kk] = LDA1(buf, m0 + s, kk);
  };
  auto RD_B2 = [&](int buf, int n0) {
#pragma unroll
    for (int kk = 0; kk < 2; kk++)
#pragma unroll
      for (int s = 0; s < 2; s++) bB[n0 + s][kk] = LDB1(buf, n0 + s, kk);
  };

  STAGE_P(0, 0, 0); STAGE_P(0, 0, 1);
  asm volatile("s_waitcnt vmcnt(0)" ::: "memory");
  __builtin_amdgcn_sched_barrier(0);

  for (int T = 0; T < NT; T++) {
    int c = T & 1, nc = c ^ 1;
    __builtin_amdgcn_s_barrier();
    if (T + 1 < NT) { STAGE_P(T + 1, nc, 0); STAGE_P(T + 1, nc, 1); }
    __builtin_amdgcn_sched_barrier(0);
    RD_A2(c, 0, 0);
    __builtin_amdgcn_sched_barrier(0);
    RD_B2(c, 0);
    __builtin_amdgcn_sched_barrier(0);
    RD_B2(c, 2);
    __builtin_amdgcn_sched_barrier(0);
    RD_A2(c, 2, 2);
    __builtin_amdgcn_sched_barrier(0);

    asm volatile("s_waitcnt lgkmcnt(8)" ::: "memory");
    __builtin_amdgcn_sched_barrier(0);
    __builtin_amdgcn_s_setprio(1);
    OCT(0, 0, 0);
    __builtin_amdgcn_s_setprio(0);
    asm volatile("s_waitcnt lgkmcnt(4)" ::: "memory");
    __builtin_amdgcn_sched_barrier(0);
    __builtin_amdgcn_s_setprio(1);
    OCT(0, 1, 0);
    __builtin_amdgcn_s_setprio(0);
    RD_A2(c, 4, 0);
    __builtin_amdgcn_sched_barrier(0);
    asm volatile("s_waitcnt lgkmcnt(4)" ::: "memory");
    __builtin_amdgcn_sched_barrier(0);
    __builtin_amdgcn_s_setprio(1);
    OCT(1, 0, 2); OCT(1, 1, 2);
    __builtin_amdgcn_s_setprio(0);
    RD_A2(c, 6, 2);
    __builtin_amdgcn_sched_barrier(0);
    asm volatile("s_waitcnt lgkmcnt(4)" ::: "memory");
    __builtin_amdgcn_sched_barrier(0);
    __builtin_amdgcn_s_setprio(1);
    OCT(2, 0, 0); OCT(2, 1, 0);
    __builtin_amdgcn_s_setprio(0);
    asm volatile("s_waitcnt lgkmcnt(0)" ::: "memory");
    __builtin_amdgcn_sched_barrier(0);
    __builtin_amdgcn_s_setprio(1);
    OCT(3, 0, 2); OCT(3, 1, 2);
    __builtin_amdgcn_s_setprio(0);
    if (T + 1 < NT) {
      asm volatile("s_waitcnt vmcnt(0)" ::: "memory");
      __builtin_amdgcn_sched_barrier(0);
    }
  }
  asm volatile("s_waitcnt vmcnt(0) lgkmcnt(0)" ::: "memory");

  unsigned short* C = Cb + (size_t)z * M * N;
#pragma unroll
  for (int m = 0; m < 8; m++)
#pragma unroll
    for (int n = 0; n < 4; n++) {
      int row0 = bm + wr * 128 + m * 16 + lq * 4;
      int col = bn + wc * 64 + n * 16 + lr;
#pragma unroll
      for (int r = 0; r < 4; r++)
        C[(size_t)(row0 + r) * N + col] = f2bf(acc[m][n][r]);
    }
}

// ---------- 256x128 bf16 GEMM, triple-buffer, 1 barrier / K-tile ----------
template <bool BF16OUT>
__global__ __launch_bounds__(512, 1) void gemmk_kernel(
    const unsigned short* __restrict__ Aq,
    const unsigned short* __restrict__ Akv,
    const unsigned short* __restrict__ W,   // [z][N][K]
    void* __restrict__ Cb) {                // [M][N]
  constexpr int M = 4096, N = 2048, K = 2048, NT = K / 64;
  __shared__ char lds[147456];
  int z = blockIdx.z;
  const unsigned short* A = (z == 0) ? Aq : Akv;
  const unsigned short* Bt = W + (size_t)z * N * K;

  int wid = blockIdx.y * 16 + blockIdx.x;
  int nid = (wid & 7) * 32 + (wid >> 3);
  int bn = (nid & 15) * 128, bm = (nid >> 4) * 256;

  int tid = threadIdx.x, wave = tid >> 6, lane = tid & 63;
  int lr = lane & 15, lq = lane >> 4;
  int wr = wave >> 1, wc = wave & 1;

  auto STAGE_U = [&](int t, int buf, int which) {
    int k0 = t * 64;
    const unsigned short* src = (which < 2) ? A : Bt;
    int rbase = (which < 2) ? (bm + which * 128) : bn;
    char* dst0 = lds + buf * 49152 + which * 16384;
#pragma unroll
    for (int i = 0; i < 2; i++) {
      int o = i * 8192 + wave * 1024 + lane * 16;
      int row = o >> 7, colb = o & 127;
      int sc = colb ^ ((row & 7) << 4);
      __builtin_amdgcn_global_load_lds(
          (gas_cvp)(src + (size_t)(rbase + row) * K + k0 + (sc >> 1)),
          (las_vp)(dst0 + i * 8192 + wave * 1024), 16, 0, 0);
    }
  };
  auto LDA = [&](int buf, int m, int kk) -> bf16x8 {
    int row = wr * 64 + m * 16 + lr;
    int half = row >> 7, r = row & 127;
    int byt = r * 128 + (((kk * 4 + lq) ^ (r & 7)) << 4);
    return *(const bf16x8*)(lds + buf * 49152 + half * 16384 + byt);
  };
  auto LDB = [&](int buf, int n, int kk) -> bf16x8 {
    int row = wc * 64 + n * 16 + lr;
    int byt = row * 128 + (((kk * 4 + lq) ^ (row & 7)) << 4);
    return *(const bf16x8*)(lds + buf * 49152 + 32768 + byt);
  };

  f32x4 acc[4][4] = {};
  bf16x8 aA[4][2], bB[4][2];

  auto QUAD = [&](int mg, int ng) {
#pragma unroll
    for (int kk = 0; kk < 2; kk++)
#pragma unroll
      for (int mm = 0; mm < 2; mm++)
#pragma unroll
        for (int nn = 0; nn < 2; nn++)
          acc[mg * 2 + mm][ng * 2 + nn] = __builtin_amdgcn_mfma_f32_16x16x32_bf16(
              aA[mg * 2 + mm][kk], bB[ng * 2 + nn][kk], acc[mg * 2 + mm][ng * 2 + nn], 0, 0, 0);
  };

  auto BODY = [&](int T, int cur, int dst, int mode) {
    __builtin_amdgcn_s_barrier();
    if (mode == 0) {
      STAGE_U(T + 2, dst, 0); STAGE_U(T + 2, dst, 1); STAGE_U(T + 2, dst, 2);
    }
    __builtin_amdgcn_sched_barrier(0);
#pragma unroll
    for (int kk = 0; kk < 2; kk++)
#pragma unroll
      for (int mm = 0; mm < 2; mm++) aA[mm][kk] = LDA(cur, mm, kk);
#pragma unroll
    for (int kk = 0; kk < 2; kk++)
#pragma unroll
      for (int nn = 0; nn < 2; nn++) bB[nn][kk] = LDB(cur, nn, kk);
    __builtin_amdgcn_sched_barrier(0);
#pragma unroll
    for (int kk = 0; kk < 2; kk++)
#pragma unroll
      for (int nn = 0; nn < 2; nn++) bB[2 + nn][kk] = LDB(cur, 2 + nn, kk);
    __builtin_amdgcn_sched_barrier(0);
#pragma unroll
    for (int kk = 0; kk < 2; kk++)
#pragma unroll
      for (int mm = 0; mm < 2; mm++) aA[2 + mm][kk] = LDA(cur, 2 + mm, kk);
    __builtin_amdgcn_sched_barrier(0);

    asm volatile("s_waitcnt lgkmcnt(8)" ::: "memory");
    __builtin_amdgcn_sched_barrier(0);
    __builtin_amdgcn_s_setprio(1);
    QUAD(0, 0);
    __builtin_amdgcn_s_setprio(0);
    asm volatile("s_waitcnt lgkmcnt(4)" ::: "memory");
    __builtin_amdgcn_sched_barrier(0);
    __builtin_amdgcn_s_setprio(1);
    QUAD(0, 1);
    __builtin_amdgcn_s_setprio(0);
    asm volatile("s_waitcnt lgkmcnt(0)" ::: "memory");
    __builtin_amdgcn_sched_barrier(0);
    __builtin_amdgcn_s_setprio(1);
    QUAD(1, 0); QUAD(1, 1);
    __builtin_amdgcn_s_setprio(0);
    if (mode == 0)      asm volatile("s_waitcnt vmcnt(6)" ::: "memory");
    else if (mode == 1) asm volatile("s_waitcnt vmcnt(0)" ::: "memory");
    __builtin_amdgcn_sched_barrier(0);
  };

  STAGE_U(0, 0, 0); STAGE_U(0, 0, 1); STAGE_U(0, 0, 2);
  STAGE_U(1, 1, 0); STAGE_U(1, 1, 1); STAGE_U(1, 1, 2);
  asm volatile("s_waitcnt vmcnt(6)" ::: "memory");
  __builtin_amdgcn_sched_barrier(0);

  int cur = 0;
  for (int T = 0; T < NT - 2; T++) {
    int dst = (cur == 0) ? 2 : cur - 1;
    BODY(T, cur, dst, 0);
    cur = (cur == 2) ? 0 : cur + 1;
  }
  BODY(NT - 2, cur, 0, 1);
  cur = (cur == 2) ? 0 : cur + 1;
  BODY(NT - 1, cur, 0, 2);
  asm volatile("s_waitcnt vmcnt(0) lgkmcnt(0)" ::: "memory");

#pragma unroll
  for (int m = 0; m < 4; m++)
#pragma unroll
    for (int n = 0; n < 4; n++) {
      int row0 = bm + wr * 64 + m * 16 + lq * 4;
      int col = bn + wc * 64 + n * 16 + lr;
      if (BF16OUT) {
        unsigned short* C = (unsigned short*)Cb;
#pragma unroll
        for (int r = 0; r < 4; r++)
          C[(size_t)(row0 + r) * N + col] = f2bf(acc[m][n][r]);
      } else {
        float* C = (float*)Cb;
#pragma unroll
        for (int r = 0; r < 4; r++)
          C[(size_t)(row0 + r) * N + col] = acc[m][n][r];
      }
    }
}

// ---------- causal flash attention, 4-wave blocks, 2 blocks/CU ----------
// grid 512 linear. Decode keeps same-(b,h) on one XCD (xcd = hb&7) and pairs
// q-tiles (j, 15-j) on the same CU (d and d+256 share a CU slot).
// Scores arrive in log2 domain (Q pre-scaled by 1/sqrt(HD)*log2e) -> exp2f.
__global__ __launch_bounds__(256, 2) void attn_kernel(const unsigned short* __restrict__ Qb,
                                                      const unsigned short* __restrict__ Kb,
                                                      const unsigned short* __restrict__ Vt,
                                                      unsigned short* __restrict__ ctx) {
  __shared__ char lds[65536];   // dbuf: [2][ K 16KB | V^T 16KB ]
  int d = blockIdx.x;
  int half = d >> 8;
  int u = d & 255;
  int hb = (u & 7) | ((u >> 6) << 3);        // 5 bits: h(4) + b(1)
  int jlo = (u >> 3) & 7;
  int h = hb & 15, b = hb >> 4;
  int qtile = half ? jlo : (15 - jlo);

  int tid = threadIdx.x, wave = tid >> 6, lane = tid & 63;
  int lr = lane & 15, lq = lane >> 4;
  int qw = qtile * 128 + wave * 32;
  int nt = 2 * qtile + 2;

  const unsigned short* Qp = Qb + (size_t)b * S_LEN * DMODEL + (size_t)h * HDIM;
  const unsigned short* Kp = Kb + (size_t)b * S_LEN * DMODEL + (size_t)h * HDIM;
  const unsigned short* Vp = Vt + (size_t)(b * NH + h) * HDIM * S_LEN;

  bf16x8 qa[2][4];
#pragma unroll
  for (int mi = 0; mi < 2; mi++)
#pragma unroll
    for (int kf = 0; kf < 4; kf++)
      qa[mi][kf] = *(const bf16x8*)(Qp + (size_t)(qw + mi * 16 + lr) * DMODEL + kf * 32 + lq * 8);

  f32x4 o[2][8] = {};
  float mrow[2] = {-1e30f, -1e30f};
  float lsum[2] = {0.f, 0.f};

  auto STAGE = [&](int tt, int bsel) {
    int kk0 = tt * 64;
#pragma unroll
    for (int i = 0; i < 4; i++) {            // K tile [64][128] bf16, 16KB
      int o_ = wave * 4096 + i * 1024 + lane * 16;
      int row = o_ >> 8, colb = o_ & 255;
      int sc_ = colb ^ ((row & 7) << 4);
      __builtin_amdgcn_global_load_lds(
          (gas_cvp)(Kp + (size_t)(kk0 + row) * DMODEL + (sc_ >> 1)),
          (las_vp)(lds + bsel * 32768 + wave * 4096 + i * 1024), 16, 0, 0);
    }
#pragma unroll
    for (int i = 0; i < 4; i++) {            // V^T tile [128][64] bf16, 16KB
      int o_ = wave * 4096 + i * 1024 + lane * 16;
      int row = o_ >> 7, colb = o_ & 127;
      int sc_ = colb ^ ((row & 7) << 4);
      __builtin_amdgcn_global_load_lds(
          (gas_cvp)(Vp + (size_t)row * S_LEN + kk0 + (sc_ >> 1)),
          (las_vp)(lds + bsel * 32768 + 16384 + wave * 4096 + i * 1024), 16, 0, 0);
    }
  };

  STAGE(0, 0);
  __syncthreads();

  for (int t = 0; t < nt; t++) {
    int cur = t & 1;
    int k0 = t * 64;
    if (t + 1 < nt) STAGE(t + 1, cur ^ 1);

    bool active = (k0 <= qw + 31);
    if (active) {
      const char* kbb = lds + cur * 32768;
      f32x4 sf[2][4] = {};
#pragma unroll
      for (int kf = 0; kf < 4; kf++) {
        bf16x8 kbf[4];
#pragma unroll
        for (int nf = 0; nf < 4; nf++) {
          int row = nf * 16 + lr;
          int colb = kf * 64 + lq * 16;
          kbf[nf] = *(const bf16x8*)(kbb + row * 256 + (colb ^ ((row & 7) << 4)));
        }
#pragma unroll
        for (int nf = 0; nf < 4; nf++)
#pragma unroll
          for (int mi = 0; mi < 2; mi++)
            sf[mi][nf] = __builtin_amdgcn_mfma_f32_16x16x32_bf16(kbf[nf], qa[mi][kf], sf[mi][nf], 0, 0, 0);
      }

      if (k0 + 63 > qw) {
#pragma unroll
        for (int mi = 0; mi < 2; mi++) {
          int q = qw + mi * 16 + lr;
#pragma unroll
          for (int nf = 0; nf < 4; nf++)
#pragma unroll
            for (int r = 0; r < 4; r++)
              if (k0 + nf * 16 + lq * 4 + r > q) sf[mi][nf][r] = -1e30f;
        }
      }

      float vmax[2];
#pragma unroll
      for (int mi = 0; mi < 2; mi++) {
        float v = sf[mi][0][0];
#pragma unroll
        for (int nf = 0; nf < 4; nf++)
#pragma unroll
          for (int r = 0; r < 4; r++) v = fmaxf(v, sf[mi][nf][r]);
        v = fmaxf(v, __shfl_xor(v, 16));
        v = fmaxf(v, __shfl_xor(v, 32));
        vmax[mi] = v;
      }
      bool need = (vmax[0] > mrow[0] + 8.f) || (vmax[1] > mrow[1] + 8.f);
      if (__any(need)) {
#pragma unroll
        for (int mi = 0; mi < 2; mi++) {
          float mn = fmaxf(mrow[mi], vmax[mi]);
          float al = exp2f(mrow[mi] - mn);
          mrow[mi] = mn;
          lsum[mi] *= al;
#pragma unroll
          for (int ff = 0; ff < 8; ff++) o[mi][ff] *= al;
        }
      }
#pragma unroll
      for (int mi = 0; mi < 2; mi++) {
        float rs = 0.f;
#pragma unroll
        for (int nf = 0; nf < 4; nf++)
#pragma unroll
          for (int r = 0; r < 4; r++) {
            float p = exp2f(sf[mi][nf][r] - mrow[mi]);
            sf[mi][nf][r] = p;
            rs += p;
          }
        rs += __shfl_xor(rs, 16);
        rs += __shfl_xor(rs, 32);
        lsum[mi] += rs;
      }

      const char* vbb = lds + cur * 32768 + 16384;
      bool hi = (lane >= 32);
      bool odd = (lq & 1);
#pragma unroll
      for (int c = 0; c < 2; c++) {
        bf16x8 pfrag[2];
#pragma unroll
        for (int mi = 0; mi < 2; mi++) {
          unsigned int A0 = cvt_pk_bf16(sf[mi][2 * c][0], sf[mi][2 * c][1]);
          unsigned int A1 = cvt_pk_bf16(sf[mi][2 * c][2], sf[mi][2 * c][3]);
          unsigned int B0 = cvt_pk_bf16(sf[mi][2 * c + 1][0], sf[mi][2 * c + 1][1]);
          unsigned int B1 = cvt_pk_bf16(sf[mi][2 * c + 1][2], sf[mi][2 * c + 1][3]);
          unsigned int sA0 = (unsigned int)__shfl_xor((int)A0, 32);
          unsigned int sA1 = (unsigned int)__shfl_xor((int)A1, 32);
          unsigned int sB0 = (unsigned int)__shfl_xor((int)B0, 32);
          unsigned int sB1 = (unsigned int)__shfl_xor((int)B1, 32);
          unsigned int Y0f = hi ? sB0 : A0, Y0s = hi ? B0 : sA0;
          unsigned int Y1f = hi ? sB1 : A1, Y1s = hi ? B1 : sA1;
          unsigned int z0 = odd ? Y0f : Y0s, z1 = odd ? Y1f : Y1s;
          unsigned int w0 = (unsigned int)__shfl_xor((int)z0, 16);
          unsigned int w1 = (unsigned int)__shfl_xor((int)z1, 16);
          int4 fr;
          fr.x = (int)(odd ? w0 : Y0f);
          fr.y = (int)(odd ? w1 : Y1f);
          fr.z = (int)(odd ? Y0s : w0);
          fr.w = (int)(odd ? Y1s : w1);
          pfrag[mi] = __builtin_bit_cast(bf16x8, fr);
        }
#pragma unroll
        for (int ff = 0; ff < 8; ff++) {
          int row = ff * 16 + lr;
          int colb = c * 64 + lq * 16;
          bf16x8 vb = *(const bf16x8*)(vbb + row * 128 + (colb ^ ((row & 7) << 4)));
#pragma unroll
          for (int mi = 0; mi < 2; mi++)
            o[mi][ff] = __builtin_amdgcn_mfma_f32_16x16x32_bf16(vb, pfrag[mi], o[mi][ff], 0, 0, 0);
        }
      }
    }

    __syncthreads();
  }

#pragma unroll
  for (int mi = 0; mi < 2; mi++) {
    float inv = 1.0f / lsum[mi];
    size_t rb = ((size_t)b * S_LEN + qw + mi * 16 + lr) * DMODEL + h * HDIM;
#pragma unroll
    for (int ff = 0; ff < 8; ff++) {
      unsigned int u0 = cvt_pk_bf16(o[mi][ff][0] * inv, o[mi][ff][1] * inv);
      unsigned int u1 = cvt_pk_bf16(o[mi][ff][2] * inv, o[mi][ff][3] * inv);
      *(uint2*)(ctx + rb + ff * 16 + lq * 4) = make_uint2(u0, u1);
    }
  }
}

extern "C" void kernel_launch(void* const* d_in, const int* in_sizes, int n_in,
                              void* d_out, int out_size, void* d_ws, size_t ws_size,
                              hipStream_t stream) {
  const float* inq  = (const float*)d_in[0];
  const float* inkv = (const float*)d_in[1];
  const float* wq   = (const float*)d_in[2];
  const float* wk   = (const float*)d_in[3];
  const float* wv   = (const float*)d_in[4];
  const float* wo   = (const float*)d_in[5];
  float* out = (float*)d_out;

  char* ws = (char*)d_ws;
  const size_t MB = 1ull << 20;
  unsigned short* xq  = (unsigned short*)(ws);             // 16 MB (reused as Qb)
  unsigned short* xkv = (unsigned short*)(ws + 16 * MB);   // 16 MB (reused as Kb)
  unsigned short* wqt = (unsigned short*)(ws + 32 * MB);   // 8 MB
  unsigned short* wvt = (unsigned short*)(ws + 48 * MB);   // 8 MB
  unsigned short* wot = (unsigned short*)(ws + 56 * MB);   // 8 MB (wqt..wot contiguous)
  float2* sc          = (float2*)(ws + 64 * MB);           // 1 MB
  unsigned short* projb = (unsigned short*)(ws + 66 * MB); // 48 MB (Q,K,V bf16)
  unsigned short* Vt   = (unsigned short*)(ws + 114 * MB); // 16 MB
  unsigned short* ctxb = (unsigned short*)(ws + 130 * MB); // 16 MB
  unsigned short* Qb = xq;    // xq dead after proj GEMMs
  unsigned short* Kb = xkv;   // xkv dead after proj GEMMs

  const int n4 = (2 * S_LEN * DMODEL) / 4;
  cvt2_kernel<<<dim3(n4 / 256, 1, 2), 256, 0, stream>>>(
      (const float4*)inq, (const float4*)inkv, (ushort4*)xq, (ushort4*)xkv, n4);

  wtrans4_kernel<<<dim3(32, 32, 4), 256, 0, stream>>>(wq, wk, wv, wo, wqt);

  sincos_kernel<<<(S_LEN * 64) / 256, 256, 0, stream>>>(sc);

  // 1/sqrt(128) * log2(e): scores computed directly in log2 domain
  const float qscale = 0.12751743249052045f;
  unsigned short* projQ = projb;
  unsigned short* projK = projb + (size_t)4096 * 2048;
  unsigned short* projV = projb + (size_t)2 * 4096 * 2048;

  // Q,K projections: 256 blocks of 256x256 = 1 exact round
  gemm256o_kernel<<<dim3(8, 16, 2), 512, 0, stream>>>(xq, xkv, wqt, projb);
  // V projection: 256 blocks of 256x128 = 1 exact round
  gemmk_kernel<true><<<dim3(16, 16, 1), 512, 0, stream>>>(xkv, xkv, wvt, (void*)projV);

  rope8_kernel<<<dim3(2048, 1, 2), 256, 0, stream>>>(projQ, projK, sc, Qb, Kb, qscale);
  vtrans_kernel<<<dim3(2, 32, 32), 256, 0, stream>>>(projV, Vt);

  attn_kernel<<<512, 256, 0, stream>>>(Qb, Kb, Vt, ctxb);

  // output projection: 256 blocks = 1 exact round
  gemmk_kernel<false><<<dim3(16, 16, 1), 512, 0, stream>>>(ctxb, ctxb, wot, (void*)out);
}

// Round 12
// 266.936 us; speedup vs baseline: 1.0022x; 1.0022x over previous
//
#include <hip/hip_runtime.h>

#define S_LEN 2048
#define NH 16
#define HDIM 128
#define DMODEL 2048

typedef __attribute__((ext_vector_type(8))) short bf16x8;
typedef __attribute__((ext_vector_type(4))) float f32x4;

using gas_cvp = const __attribute__((address_space(1))) void*;
using las_vp  = __attribute__((address_space(3))) void*;

__device__ __forceinline__ unsigned short f2bf(float x) {
  unsigned int u = __builtin_bit_cast(unsigned int, x);
  u += 0x7FFFu + ((u >> 16) & 1u);
  return (unsigned short)(u >> 16);
}
__device__ __forceinline__ float bf2f(unsigned short u) {
  unsigned int x = ((unsigned int)u) << 16;
  return __builtin_bit_cast(float, x);
}
__device__ __forceinline__ unsigned int cvt_pk_bf16(float lo, float hi) {
  unsigned int r;
  asm("v_cvt_pk_bf16_f32 %0, %1, %2" : "=v"(r) : "v"(lo), "v"(hi));
  return r;
}

// ---------- fp32 -> bf16 convert, both inputs in one dispatch ----------
__global__ __launch_bounds__(256) void cvt2_kernel(const float4* __restrict__ inq,
                                                   const float4* __restrict__ inkv,
                                                   ushort4* __restrict__ outq,
                                                   ushort4* __restrict__ outkv, int n4) {
  const float4* in = blockIdx.z ? inkv : inq;
  ushort4* out = blockIdx.z ? outkv : outq;
  int i = blockIdx.x * 256 + threadIdx.x;
  if (i < n4) {
    float4 v = in[i];
    ushort4 r;
    r.x = f2bf(v.x); r.y = f2bf(v.y); r.z = f2bf(v.z); r.w = f2bf(v.w);
    out[i] = r;
  }
}

// ---------- sin/cos table ----------
__global__ __launch_bounds__(256) void sincos_kernel(float2* __restrict__ sc) {
  int i = blockIdx.x * 256 + threadIdx.x;
  int s = i >> 6, j = i & 63;
  float inv_ts = 1.0f / powf(10000.0f, (float)j * (1.0f / 64.0f));
  float ang = (float)s * inv_ts;
  sc[i] = make_float2(sinf(ang), cosf(ang));
}

// ---------- RoPE (+scale), z=0: Q (scaled by 1/sqrt(HD)*log2e), z=1: K ----------
__global__ __launch_bounds__(256) void rope8_kernel(const unsigned short* __restrict__ XQ,
                                                    const unsigned short* __restrict__ XK,
                                                    const float2* __restrict__ sc,
                                                    unsigned short* __restrict__ outQ,
                                                    unsigned short* __restrict__ outK,
                                                    float qscale) {
  const unsigned short* X = blockIdx.z ? XK : XQ;
  unsigned short* out = blockIdx.z ? outK : outQ;
  float scale = blockIdx.z ? 1.0f : qscale;
  int i = blockIdx.x * 256 + threadIdx.x;   // [4096][16][8]
  int m = i >> 7;
  int r = i & 127;
  int h = r >> 3, jb = (r & 7) * 8;
  int s = m & (S_LEN - 1);
  size_t base = (size_t)m * DMODEL + h * HDIM + jb;
  int4 x1 = *(const int4*)(X + base);
  int4 x2 = *(const int4*)(X + base + 64);
  const float2* pp = sc + s * 64 + jb;
  int4 o1, o2;
  int* x1w = (int*)&x1; int* x2w = (int*)&x2;
  int* o1w = (int*)&o1; int* o2w = (int*)&o2;
#pragma unroll
  for (int w = 0; w < 4; w++) {
    float a_lo = bf2f((unsigned short)(x1w[w] & 0xffff));
    float a_hi = bf2f((unsigned short)((unsigned int)x1w[w] >> 16));
    float b_lo = bf2f((unsigned short)(x2w[w] & 0xffff));
    float b_hi = bf2f((unsigned short)((unsigned int)x2w[w] >> 16));
    float2 c0 = pp[w * 2], c1 = pp[w * 2 + 1];
    float r1l = (a_lo * c0.y - b_lo * c0.x) * scale;
    float r1h = (a_hi * c1.y - b_hi * c1.x) * scale;
    float r2l = (b_lo * c0.y + a_lo * c0.x) * scale;
    float r2h = (b_hi * c1.y + a_hi * c1.x) * scale;
    o1w[w] = (int)(cvt_pk_bf16(r1l, r1h));
    o2w[w] = (int)(cvt_pk_bf16(r2l, r2h));
  }
  *(int4*)(out + base) = o1;
  *(int4*)(out + base + 64) = o2;
}

// ---------- 2048x2048 weight transpose + convert, 4 weights ----------
__global__ __launch_bounds__(256) void wtrans4_kernel(const float* __restrict__ w0,
                                                      const float* __restrict__ w1,
                                                      const float* __restrict__ w2,
                                                      const float* __restrict__ w3,
                                                      unsigned short* __restrict__ outb) {
  __shared__ float tile[64][65];
  int z = blockIdx.z;
  const float* in = (z == 0) ? w0 : (z == 1) ? w1 : (z == 2) ? w2 : w3;
  unsigned short* out = outb + (size_t)z * DMODEL * DMODEL;
  int c0 = blockIdx.x * 64, r0 = blockIdx.y * 64;
  int tx = threadIdx.x & 63, ty = threadIdx.x >> 6;
#pragma unroll
  for (int i = 0; i < 16; i++) {
    int r = ty + i * 4;
    tile[r][tx] = in[(size_t)(r0 + r) * DMODEL + c0 + tx];
  }
  __syncthreads();
#pragma unroll
  for (int i = 0; i < 16; i++) {
    int c = ty + i * 4;
    out[(size_t)(c0 + c) * DMODEL + r0 + tx] = f2bf(tile[tx][c]);
  }
}

// ---------- V transpose: [B,S,H,HD] bf16 -> [B,H,HD,S] bf16 ----------
__global__ __launch_bounds__(256) void vtrans_kernel(const unsigned short* __restrict__ vf,
                                                     unsigned short* __restrict__ Vt) {
  __shared__ unsigned short tile[64][65];
  int z = blockIdx.z; int b = z >> 4, h = z & 15;
  const unsigned short* I = vf + (size_t)b * S_LEN * DMODEL + h * HDIM;
  unsigned short* O = Vt + (size_t)z * HDIM * S_LEN;
  int s0 = blockIdx.y * 64, f0 = blockIdx.x * 64;
  int tx = threadIdx.x & 63, ty = threadIdx.x >> 6;
#pragma unroll
  for (int i = 0; i < 16; i++) {
    int r = ty + i * 4;
    tile[r][tx] = I[(size_t)(s0 + r) * DMODEL + f0 + tx];
  }
  __syncthreads();
#pragma unroll
  for (int i = 0; i < 16; i++) {
    int c = ty + i * 4;
    O[(size_t)(f0 + c) * S_LEN + s0 + tx] = tile[tx][c];
  }
}

// ---------- 256x256 bf16 GEMM, octet pipeline, 1 barrier / K-tile ----------
__global__ __launch_bounds__(512, 1) void gemm256o_kernel(
    const unsigned short* __restrict__ Aq,
    const unsigned short* __restrict__ Akv,
    const unsigned short* __restrict__ W,    // [z][N][K]
    unsigned short* __restrict__ Cb) {       // [z][M][N] bf16
  constexpr int M = 4096, N = 2048, K = 2048, NT = K / 64;
  __shared__ char lds[131072];
  int wid = blockIdx.z * 128 + blockIdx.y * 8 + blockIdx.x;
  int nid = (wid & 7) * 32 + (wid >> 3);
  int z = nid >> 7;
  int rem = nid & 127;
  int bm = (rem >> 3) * 256, bn = (rem & 7) * 256;
  const unsigned short* A = (z == 0) ? Aq : Akv;
  const unsigned short* Bt = W + (size_t)z * N * K;

  int tid = threadIdx.x, wave = tid >> 6, lane = tid & 63;
  int lr = lane & 15, lq = lane >> 4;
  int wr = wave >> 2, wc = wave & 3;

  auto STAGE_P = [&](int t, int buf, int isB) {
    int k0 = t * 64;
    const unsigned short* src = isB ? Bt : A;
    int rbase = isB ? bn : bm;
    char* dst0 = lds + buf * 65536 + isB * 32768;
#pragma unroll
    for (int i = 0; i < 4; i++) {
      int o = i * 8192 + tid * 16;
      int row = o >> 7, colb = o & 127;
      int sc = colb ^ ((row & 7) << 4);
      __builtin_amdgcn_global_load_lds(
          (gas_cvp)(src + (size_t)(rbase + row) * K + k0 + (sc >> 1)),
          (las_vp)(dst0 + i * 8192 + wave * 1024), 16, 0, 0);
    }
  };
  auto LDA1 = [&](int buf, int m, int kk) -> bf16x8 {
    int row = wr * 128 + m * 16 + lr;
    return *(const bf16x8*)(lds + buf * 65536 + row * 128 +
                            (((kk * 4 + lq) ^ (row & 7)) << 4));
  };
  auto LDB1 = [&](int buf, int n, int kk) -> bf16x8 {
    int row = wc * 64 + n * 16 + lr;
    return *(const bf16x8*)(lds + buf * 65536 + 32768 + row * 128 +
                            (((kk * 4 + lq) ^ (row & 7)) << 4));
  };

  f32x4 acc[8][4] = {};
  bf16x8 aA[4][2], bB[4][2];

  auto OCT = [&](int P, int Q, int sb) {
#pragma unroll
    for (int kk = 0; kk < 2; kk++)
#pragma unroll
      for (int s = 0; s < 2; s++)
#pragma unroll
        for (int nn = 0; nn < 2; nn++)
          acc[2 * P + s][2 * Q + nn] = __builtin_amdgcn_mfma_f32_16x16x32_bf16(
              aA[sb + s][kk], bB[2 * Q + nn][kk], acc[2 * P + s][2 * Q + nn], 0, 0, 0);
  };
  auto RD_A2 = [&](int buf, int m0, int sb) {
#pragma unroll
    for (int kk = 0; kk < 2; kk++)
#pragma unroll
      for (int s = 0; s < 2; s++) aA[sb + s][kk] = LDA1(buf, m0 + s, kk);
  };
  auto RD_B2 = [&](int buf, int n0) {
#pragma unroll
    for (int kk = 0; kk < 2; kk++)
#pragma unroll
      for (int s = 0; s < 2; s++) bB[n0 + s][kk] = LDB1(buf, n0 + s, kk);
  };

  STAGE_P(0, 0, 0); STAGE_P(0, 0, 1);
  asm volatile("s_waitcnt vmcnt(0)" ::: "memory");
  __builtin_amdgcn_sched_barrier(0);

  for (int T = 0; T < NT; T++) {
    int c = T & 1, nc = c ^ 1;
    __builtin_amdgcn_s_barrier();
    if (T + 1 < NT) { STAGE_P(T + 1, nc, 0); STAGE_P(T + 1, nc, 1); }
    __builtin_amdgcn_sched_barrier(0);
    RD_A2(c, 0, 0);
    __builtin_amdgcn_sched_barrier(0);
    RD_B2(c, 0);
    __builtin_amdgcn_sched_barrier(0);
    RD_B2(c, 2);
    __builtin_amdgcn_sched_barrier(0);
    RD_A2(c, 2, 2);
    __builtin_amdgcn_sched_barrier(0);

    asm volatile("s_waitcnt lgkmcnt(8)" ::: "memory");
    __builtin_amdgcn_sched_barrier(0);
    __builtin_amdgcn_s_setprio(1);
    OCT(0, 0, 0);
    __builtin_amdgcn_s_setprio(0);
    asm volatile("s_waitcnt lgkmcnt(4)" ::: "memory");
    __builtin_amdgcn_sched_barrier(0);
    __builtin_amdgcn_s_setprio(1);
    OCT(0, 1, 0);
    __builtin_amdgcn_s_setprio(0);
    RD_A2(c, 4, 0);
    __builtin_amdgcn_sched_barrier(0);
    asm volatile("s_waitcnt lgkmcnt(4)" ::: "memory");
    __builtin_amdgcn_sched_barrier(0);
    __builtin_amdgcn_s_setprio(1);
    OCT(1, 0, 2); OCT(1, 1, 2);
    __builtin_amdgcn_s_setprio(0);
    RD_A2(c, 6, 2);
    __builtin_amdgcn_sched_barrier(0);
    asm volatile("s_waitcnt lgkmcnt(4)" ::: "memory");
    __builtin_amdgcn_sched_barrier(0);
    __builtin_amdgcn_s_setprio(1);
    OCT(2, 0, 0); OCT(2, 1, 0);
    __builtin_amdgcn_s_setprio(0);
    asm volatile("s_waitcnt lgkmcnt(0)" ::: "memory");
    __builtin_amdgcn_sched_barrier(0);
    __builtin_amdgcn_s_setprio(1);
    OCT(3, 0, 2); OCT(3, 1, 2);
    __builtin_amdgcn_s_setprio(0);
    if (T + 1 < NT) {
      asm volatile("s_waitcnt vmcnt(0)" ::: "memory");
      __builtin_amdgcn_sched_barrier(0);
    }
  }
  asm volatile("s_waitcnt vmcnt(0) lgkmcnt(0)" ::: "memory");

  unsigned short* C = Cb + (size_t)z * M * N;
#pragma unroll
  for (int m = 0; m < 8; m++)
#pragma unroll
    for (int n = 0; n < 4; n++) {
      int row0 = bm + wr * 128 + m * 16 + lq * 4;
      int col = bn + wc * 64 + n * 16 + lr;
#pragma unroll
      for (int r = 0; r < 4; r++)
        C[(size_t)(row0 + r) * N + col] = f2bf(acc[m][n][r]);
    }
}

// ---------- 256x128 bf16 GEMM, triple-buffer, 1 barrier / K-tile ----------
template <bool BF16OUT>
__global__ __launch_bounds__(512, 1) void gemmk_kernel(
    const unsigned short* __restrict__ Aq,
    const unsigned short* __restrict__ Akv,
    const unsigned short* __restrict__ W,   // [z][N][K]
    void* __restrict__ Cb) {                // [M][N]
  constexpr int M = 4096, N = 2048, K = 2048, NT = K / 64;
  __shared__ char lds[147456];
  int z = blockIdx.z;
  const unsigned short* A = (z == 0) ? Aq : Akv;
  const unsigned short* Bt = W + (size_t)z * N * K;

  int wid = blockIdx.y * 16 + blockIdx.x;
  int nid = (wid & 7) * 32 + (wid >> 3);
  int bn = (nid & 15) * 128, bm = (nid >> 4) * 256;

  int tid = threadIdx.x, wave = tid >> 6, lane = tid & 63;
  int lr = lane & 15, lq = lane >> 4;
  int wr = wave >> 1, wc = wave & 1;

  auto STAGE_U = [&](int t, int buf, int which) {
    int k0 = t * 64;
    const unsigned short* src = (which < 2) ? A : Bt;
    int rbase = (which < 2) ? (bm + which * 128) : bn;
    char* dst0 = lds + buf * 49152 + which * 16384;
#pragma unroll
    for (int i = 0; i < 2; i++) {
      int o = i * 8192 + wave * 1024 + lane * 16;
      int row = o >> 7, colb = o & 127;
      int sc = colb ^ ((row & 7) << 4);
      __builtin_amdgcn_global_load_lds(
          (gas_cvp)(src + (size_t)(rbase + row) * K + k0 + (sc >> 1)),
          (las_vp)(dst0 + i * 8192 + wave * 1024), 16, 0, 0);
    }
  };
  auto LDA = [&](int buf, int m, int kk) -> bf16x8 {
    int row = wr * 64 + m * 16 + lr;
    int half = row >> 7, r = row & 127;
    int byt = r * 128 + (((kk * 4 + lq) ^ (r & 7)) << 4);
    return *(const bf16x8*)(lds + buf * 49152 + half * 16384 + byt);
  };
  auto LDB = [&](int buf, int n, int kk) -> bf16x8 {
    int row = wc * 64 + n * 16 + lr;
    int byt = row * 128 + (((kk * 4 + lq) ^ (row & 7)) << 4);
    return *(const bf16x8*)(lds + buf * 49152 + 32768 + byt);
  };

  f32x4 acc[4][4] = {};
  bf16x8 aA[4][2], bB[4][2];

  auto QUAD = [&](int mg, int ng) {
#pragma unroll
    for (int kk = 0; kk < 2; kk++)
#pragma unroll
      for (int mm = 0; mm < 2; mm++)
#pragma unroll
        for (int nn = 0; nn < 2; nn++)
          acc[mg * 2 + mm][ng * 2 + nn] = __builtin_amdgcn_mfma_f32_16x16x32_bf16(
              aA[mg * 2 + mm][kk], bB[ng * 2 + nn][kk], acc[mg * 2 + mm][ng * 2 + nn], 0, 0, 0);
  };

  auto BODY = [&](int T, int cur, int dst, int mode) {
    __builtin_amdgcn_s_barrier();
    if (mode == 0) {
      STAGE_U(T + 2, dst, 0); STAGE_U(T + 2, dst, 1); STAGE_U(T + 2, dst, 2);
    }
    __builtin_amdgcn_sched_barrier(0);
#pragma unroll
    for (int kk = 0; kk < 2; kk++)
#pragma unroll
      for (int mm = 0; mm < 2; mm++) aA[mm][kk] = LDA(cur, mm, kk);
#pragma unroll
    for (int kk = 0; kk < 2; kk++)
#pragma unroll
      for (int nn = 0; nn < 2; nn++) bB[nn][kk] = LDB(cur, nn, kk);
    __builtin_amdgcn_sched_barrier(0);
#pragma unroll
    for (int kk = 0; kk < 2; kk++)
#pragma unroll
      for (int nn = 0; nn < 2; nn++) bB[2 + nn][kk] = LDB(cur, 2 + nn, kk);
    __builtin_amdgcn_sched_barrier(0);
#pragma unroll
    for (int kk = 0; kk < 2; kk++)
#pragma unroll
      for (int mm = 0; mm < 2; mm++) aA[2 + mm][kk] = LDA(cur, 2 + mm, kk);
    __builtin_amdgcn_sched_barrier(0);

    asm volatile("s_waitcnt lgkmcnt(8)" ::: "memory");
    __builtin_amdgcn_sched_barrier(0);
    __builtin_amdgcn_s_setprio(1);
    QUAD(0, 0);
    __builtin_amdgcn_s_setprio(0);
    asm volatile("s_waitcnt lgkmcnt(4)" ::: "memory");
    __builtin_amdgcn_sched_barrier(0);
    __builtin_amdgcn_s_setprio(1);
    QUAD(0, 1);
    __builtin_amdgcn_s_setprio(0);
    asm volatile("s_waitcnt lgkmcnt(0)" ::: "memory");
    __builtin_amdgcn_sched_barrier(0);
    __builtin_amdgcn_s_setprio(1);
    QUAD(1, 0); QUAD(1, 1);
    __builtin_amdgcn_s_setprio(0);
    if (mode == 0)      asm volatile("s_waitcnt vmcnt(6)" ::: "memory");
    else if (mode == 1) asm volatile("s_waitcnt vmcnt(0)" ::: "memory");
    __builtin_amdgcn_sched_barrier(0);
  };

  STAGE_U(0, 0, 0); STAGE_U(0, 0, 1); STAGE_U(0, 0, 2);
  STAGE_U(1, 1, 0); STAGE_U(1, 1, 1); STAGE_U(1, 1, 2);
  asm volatile("s_waitcnt vmcnt(6)" ::: "memory");
  __builtin_amdgcn_sched_barrier(0);

  int cur = 0;
  for (int T = 0; T < NT - 2; T++) {
    int dst = (cur == 0) ? 2 : cur - 1;
    BODY(T, cur, dst, 0);
    cur = (cur == 2) ? 0 : cur + 1;
  }
  BODY(NT - 2, cur, 0, 1);
  cur = (cur == 2) ? 0 : cur + 1;
  BODY(NT - 1, cur, 0, 2);
  asm volatile("s_waitcnt vmcnt(0) lgkmcnt(0)" ::: "memory");

#pragma unroll
  for (int m = 0; m < 4; m++)
#pragma unroll
    for (int n = 0; n < 4; n++) {
      int row0 = bm + wr * 64 + m * 16 + lq * 4;
      int col = bn + wc * 64 + n * 16 + lr;
      if (BF16OUT) {
        unsigned short* C = (unsigned short*)Cb;
#pragma unroll
        for (int r = 0; r < 4; r++)
          C[(size_t)(row0 + r) * N + col] = f2bf(acc[m][n][r]);
      } else {
        float* C = (float*)Cb;
#pragma unroll
        for (int r = 0; r < 4; r++)
          C[(size_t)(row0 + r) * N + col] = acc[m][n][r];
      }
    }
}

// ---------- causal flash attention, 8 waves, paired q-tiles, pipelined LDS ----------
// r10 structure (grid 256, in-block pairing) + per-wave read/MFMA pipelining:
// K fragments double-banked (read kf+1 under MFMA kf); V fragments in 4-reg
// quarters issued ahead of their PV octets; setprio around MFMA clusters.
__global__ __launch_bounds__(512, 1) void attn_kernel(const unsigned short* __restrict__ Qb,
                                                      const unsigned short* __restrict__ Kb,
                                                      const unsigned short* __restrict__ Vt,
                                                      unsigned short* __restrict__ ctx) {
  __shared__ char lds[65536];   // dbuf: [2][ K 16KB | V^T 16KB ]
  int d = blockIdx.x + 8 * (blockIdx.y + 16 * blockIdx.z);
  int jlo = (d >> 3) & 7;
  int hb = (d & 7) * 4 + (d >> 6);
  int h = hb & 15, b = hb >> 4;

  int tid = threadIdx.x, wave = tid >> 6, lane = tid & 63;
  int lr = lane & 15, lq = lane >> 4;
  int grp = wave >> 2, wsub = wave & 3;
  int qtile = grp ? (15 - jlo) : jlo;
  int qw = qtile * 128 + wsub * 32;
  int nt = 2 * (15 - jlo) + 2;

  const unsigned short* Qp = Qb + (size_t)b * S_LEN * DMODEL + (size_t)h * HDIM;
  const unsigned short* Kp = Kb + (size_t)b * S_LEN * DMODEL + (size_t)h * HDIM;
  const unsigned short* Vp = Vt + (size_t)(b * NH + h) * HDIM * S_LEN;

  bf16x8 qa[2][4];
#pragma unroll
  for (int mi = 0; mi < 2; mi++)
#pragma unroll
    for (int kf = 0; kf < 4; kf++)
      qa[mi][kf] = *(const bf16x8*)(Qp + (size_t)(qw + mi * 16 + lr) * DMODEL + kf * 32 + lq * 8);

  f32x4 o[2][8] = {};
  float mrow[2] = {-1e30f, -1e30f};
  float lsum[2] = {0.f, 0.f};
  bool hi = (lane >= 32);
  bool odd = (lq & 1);

  auto STAGE = [&](int tt, int bsel) {
    int kk0 = tt * 64;
#pragma unroll
    for (int i = 0; i < 2; i++) {
      int o_ = wave * 2048 + i * 1024 + lane * 16;
      int row = o_ >> 8, colb = o_ & 255;
      int sc_ = colb ^ ((row & 7) << 4);
      __builtin_amdgcn_global_load_lds(
          (gas_cvp)(Kp + (size_t)(kk0 + row) * DMODEL + (sc_ >> 1)),
          (las_vp)(lds + bsel * 32768 + wave * 2048 + i * 1024), 16, 0, 0);
    }
#pragma unroll
    for (int i = 0; i < 2; i++) {
      int o_ = wave * 2048 + i * 1024 + lane * 16;
      int row = o_ >> 7, colb = o_ & 127;
      int sc_ = colb ^ ((row & 7) << 4);
      __builtin_amdgcn_global_load_lds(
          (gas_cvp)(Vp + (size_t)row * S_LEN + kk0 + (sc_ >> 1)),
          (las_vp)(lds + bsel * 32768 + 16384 + wave * 2048 + i * 1024), 16, 0, 0);
    }
  };

  STAGE(0, 0);
  __syncthreads();

  for (int t = 0; t < nt; t++) {
    int cur = t & 1;
    int k0 = t * 64;
    if (t + 1 < nt) STAGE(t + 1, cur ^ 1);

    bool active = (k0 <= qw + 31);
    if (active) {
      const char* kbb = lds + cur * 32768;
      const char* vbb = lds + cur * 32768 + 16384;

      auto RD_K = [&](int kf, bf16x8 (&dst)[4]) {
#pragma unroll
        for (int nf = 0; nf < 4; nf++) {
          int row = nf * 16 + lr;
          int colb = kf * 64 + lq * 16;
          dst[nf] = *(const bf16x8*)(kbb + row * 256 + (colb ^ ((row & 7) << 4)));
        }
      };
      auto RD_V4 = [&](int c, int half, bf16x8 (&dst)[4]) {
#pragma unroll
        for (int f = 0; f < 4; f++) {
          int row = (half * 4 + f) * 16 + lr;
          int colb = c * 64 + lq * 16;
          dst[f] = *(const bf16x8*)(vbb + row * 128 + (colb ^ ((row & 7) << 4)));
        }
      };

      f32x4 sf[2][4] = {};
      bf16x8 kb0[4], kb1[4];
      auto QKM = [&](bf16x8 (&bank)[4], int kf) {
#pragma unroll
        for (int nf = 0; nf < 4; nf++)
#pragma unroll
          for (int mi = 0; mi < 2; mi++)
            sf[mi][nf] = __builtin_amdgcn_mfma_f32_16x16x32_bf16(bank[nf], qa[mi][kf], sf[mi][nf], 0, 0, 0);
      };

      // QK with double-banked K reads: read kf+1 while MFMA kf
      RD_K(0, kb0);
      RD_K(1, kb1);
      __builtin_amdgcn_sched_barrier(0);
      __builtin_amdgcn_s_setprio(1); QKM(kb0, 0); __builtin_amdgcn_s_setprio(0);
      RD_K(2, kb0);
      __builtin_amdgcn_sched_barrier(0);
      __builtin_amdgcn_s_setprio(1); QKM(kb1, 1); __builtin_amdgcn_s_setprio(0);
      RD_K(3, kb1);
      __builtin_amdgcn_sched_barrier(0);
      __builtin_amdgcn_s_setprio(1); QKM(kb0, 2); QKM(kb1, 3); __builtin_amdgcn_s_setprio(0);

      // issue first V quarters early: they complete under softmax VALU/shuffles
      bf16x8 va[4], vz[4];
      RD_V4(0, 0, va);
      RD_V4(0, 1, vz);
      __builtin_amdgcn_sched_barrier(0);

      // mask; softmax in log2 domain
      if (k0 + 63 > qw) {
#pragma unroll
        for (int mi = 0; mi < 2; mi++) {
          int q = qw + mi * 16 + lr;
#pragma unroll
          for (int nf = 0; nf < 4; nf++)
#pragma unroll
            for (int r = 0; r < 4; r++)
              if (k0 + nf * 16 + lq * 4 + r > q) sf[mi][nf][r] = -1e30f;
        }
      }
      float vmax[2];
#pragma unroll
      for (int mi = 0; mi < 2; mi++) {
        float v = sf[mi][0][0];
#pragma unroll
        for (int nf = 0; nf < 4; nf++)
#pragma unroll
          for (int r = 0; r < 4; r++) v = fmaxf(v, sf[mi][nf][r]);
        v = fmaxf(v, __shfl_xor(v, 16));
        v = fmaxf(v, __shfl_xor(v, 32));
        vmax[mi] = v;
      }
      bool need = (vmax[0] > mrow[0] + 8.f) || (vmax[1] > mrow[1] + 8.f);
      if (__any(need)) {
#pragma unroll
        for (int mi = 0; mi < 2; mi++) {
          float mn = fmaxf(mrow[mi], vmax[mi]);
          float al = exp2f(mrow[mi] - mn);
          mrow[mi] = mn;
          lsum[mi] *= al;
#pragma unroll
          for (int ff = 0; ff < 8; ff++) o[mi][ff] *= al;
        }
      }
#pragma unroll
      for (int mi = 0; mi < 2; mi++) {
        float rs = 0.f;
#pragma unroll
        for (int nf = 0; nf < 4; nf++)
#pragma unroll
          for (int r = 0; r < 4; r++) {
            float p = exp2f(sf[mi][nf][r] - mrow[mi]);
            sf[mi][nf][r] = p;
            rs += p;
          }
        rs += __shfl_xor(rs, 16);
        rs += __shfl_xor(rs, 32);
        lsum[mi] += rs;
      }

      auto REPACK = [&](int c, bf16x8 (&pf)[2]) {
#pragma unroll
        for (int mi = 0; mi < 2; mi++) {
          unsigned int A0 = cvt_pk_bf16(sf[mi][2 * c][0], sf[mi][2 * c][1]);
          unsigned int A1 = cvt_pk_bf16(sf[mi][2 * c][2], sf[mi][2 * c][3]);
          unsigned int B0 = cvt_pk_bf16(sf[mi][2 * c + 1][0], sf[mi][2 * c + 1][1]);
          unsigned int B1 = cvt_pk_bf16(sf[mi][2 * c + 1][2], sf[mi][2 * c + 1][3]);
          unsigned int sA0 = (unsigned int)__shfl_xor((int)A0, 32);
          unsigned int sA1 = (unsigned int)__shfl_xor((int)A1, 32);
          unsigned int sB0 = (unsigned int)__shfl_xor((int)B0, 32);
          unsigned int sB1 = (unsigned int)__shfl_xor((int)B1, 32);
          unsigned int Y0f = hi ? sB0 : A0, Y0s = hi ? B0 : sA0;
          unsigned int Y1f = hi ? sB1 : A1, Y1s = hi ? B1 : sA1;
          unsigned int z0 = odd ? Y0f : Y0s, z1 = odd ? Y1f : Y1s;
          unsigned int w0 = (unsigned int)__shfl_xor((int)z0, 16);
          unsigned int w1 = (unsigned int)__shfl_xor((int)z1, 16);
          int4 fr;
          fr.x = (int)(odd ? w0 : Y0f);
          fr.y = (int)(odd ? w1 : Y1f);
          fr.z = (int)(odd ? Y0s : w0);
          fr.w = (int)(odd ? Y1s : w1);
          pf[mi] = __builtin_bit_cast(bf16x8, fr);
        }
      };
      auto PVQ = [&](bf16x8 (&bank)[4], int half, bf16x8 (&pf)[2]) {
#pragma unroll
        for (int f = 0; f < 4; f++)
#pragma unroll
          for (int mi = 0; mi < 2; mi++)
            o[mi][half * 4 + f] = __builtin_amdgcn_mfma_f32_16x16x32_bf16(bank[f], pf[mi], o[mi][half * 4 + f], 0, 0, 0);
      };

      bf16x8 pf0[2], pf1[2];
      REPACK(0, pf0);                       // shuffles drain va/vz reads
      __builtin_amdgcn_s_setprio(1); PVQ(va, 0, pf0); __builtin_amdgcn_s_setprio(0);
      RD_V4(1, 0, va);                      // c=1 first quarter under PV(c0,h1)
      __builtin_amdgcn_sched_barrier(0);
      __builtin_amdgcn_s_setprio(1); PVQ(vz, 1, pf0); __builtin_amdgcn_s_setprio(0);
      REPACK(1, pf1);                       // shuffles drain va reads
      RD_V4(1, 1, vz);
      __builtin_amdgcn_sched_barrier(0);
      __builtin_amdgcn_s_setprio(1); PVQ(va, 0, pf1); PVQ(vz, 1, pf1); __builtin_amdgcn_s_setprio(0);
    }

    __syncthreads();
  }

#pragma unroll
  for (int mi = 0; mi < 2; mi++) {
    float inv = 1.0f / lsum[mi];
    size_t rb = ((size_t)b * S_LEN + qw + mi * 16 + lr) * DMODEL + h * HDIM;
#pragma unroll
    for (int ff = 0; ff < 8; ff++) {
      unsigned int u0 = cvt_pk_bf16(o[mi][ff][0] * inv, o[mi][ff][1] * inv);
      unsigned int u1 = cvt_pk_bf16(o[mi][ff][2] * inv, o[mi][ff][3] * inv);
      *(uint2*)(ctx + rb + ff * 16 + lq * 4) = make_uint2(u0, u1);
    }
  }
}

extern "C" void kernel_launch(void* const* d_in, const int* in_sizes, int n_in,
                              void* d_out, int out_size, void* d_ws, size_t ws_size,
                              hipStream_t stream) {
  const float* inq  = (const float*)d_in[0];
  const float* inkv = (const float*)d_in[1];
  const float* wq   = (const float*)d_in[2];
  const float* wk   = (const float*)d_in[3];
  const float* wv   = (const float*)d_in[4];
  const float* wo   = (const float*)d_in[5];
  float* out = (float*)d_out;

  char* ws = (char*)d_ws;
  const size_t MB = 1ull << 20;
  unsigned short* xq  = (unsigned short*)(ws);             // 16 MB (reused as Qb)
  unsigned short* xkv = (unsigned short*)(ws + 16 * MB);   // 16 MB (reused as Kb)
  unsigned short* wqt = (unsigned short*)(ws + 32 * MB);   // 8 MB
  unsigned short* wvt = (unsigned short*)(ws + 48 * MB);   // 8 MB
  unsigned short* wot = (unsigned short*)(ws + 56 * MB);   // 8 MB (wqt..wot contiguous)
  float2* sc          = (float2*)(ws + 64 * MB);           // 1 MB
  unsigned short* projb = (unsigned short*)(ws + 66 * MB); // 48 MB (Q,K,V bf16)
  unsigned short* Vt   = (unsigned short*)(ws + 114 * MB); // 16 MB
  unsigned short* ctxb = (unsigned short*)(ws + 130 * MB); // 16 MB
  unsigned short* Qb = xq;    // xq dead after proj GEMMs
  unsigned short* Kb = xkv;   // xkv dead after proj GEMMs

  const int n4 = (2 * S_LEN * DMODEL) / 4;
  cvt2_kernel<<<dim3(n4 / 256, 1, 2), 256, 0, stream>>>(
      (const float4*)inq, (const float4*)inkv, (ushort4*)xq, (ushort4*)xkv, n4);

  wtrans4_kernel<<<dim3(32, 32, 4), 256, 0, stream>>>(wq, wk, wv, wo, wqt);

  sincos_kernel<<<(S_LEN * 64) / 256, 256, 0, stream>>>(sc);

  // 1/sqrt(128) * log2(e): scores computed directly in log2 domain
  const float qscale = 0.12751743249052045f;
  unsigned short* projQ = projb;
  unsigned short* projK = projb + (size_t)4096 * 2048;
  unsigned short* projV = projb + (size_t)2 * 4096 * 2048;

  // Q,K projections: 256 blocks of 256x256 = 1 exact round
  gemm256o_kernel<<<dim3(8, 16, 2), 512, 0, stream>>>(xq, xkv, wqt, projb);
  // V projection: 256 blocks of 256x128 = 1 exact round
  gemmk_kernel<true><<<dim3(16, 16, 1), 512, 0, stream>>>(xkv, xkv, wvt, (void*)projV);

  rope8_kernel<<<dim3(2048, 1, 2), 256, 0, stream>>>(projQ, projK, sc, Qb, Kb, qscale);
  vtrans_kernel<<<dim3(2, 32, 32), 256, 0, stream>>>(projV, Vt);

  attn_kernel<<<dim3(8, NH, 2), 512, 0, stream>>>(Qb, Kb, Vt, ctxb);

  // output projection: 256 blocks = 1 exact round
  gemmk_kernel<false><<<dim3(16, 16, 1), 512, 0, stream>>>(ctxb, ctxb, wot, (void*)out);
}

// Round 13
// 259.470 us; speedup vs baseline: 1.0310x; 1.0288x over previous
//
#include <hip/hip_runtime.h>

#define S_LEN 2048
#define NH 16
#define HDIM 128
#define DMODEL 2048

typedef __attribute__((ext_vector_type(8))) short bf16x8;
typedef __attribute__((ext_vector_type(4))) float f32x4;

using gas_cvp = const __attribute__((address_space(1))) void*;
using las_vp  = __attribute__((address_space(3))) void*;

__device__ __forceinline__ unsigned short f2bf(float x) {
  unsigned int u = __builtin_bit_cast(unsigned int, x);
  u += 0x7FFFu + ((u >> 16) & 1u);
  return (unsigned short)(u >> 16);
}
__device__ __forceinline__ float bf2f(unsigned short u) {
  unsigned int x = ((unsigned int)u) << 16;
  return __builtin_bit_cast(float, x);
}
__device__ __forceinline__ unsigned int cvt_pk_bf16(float lo, float hi) {
  unsigned int r;
  asm("v_cvt_pk_bf16_f32 %0, %1, %2" : "=v"(r) : "v"(lo), "v"(hi));
  return r;
}

// ---------- fp32 -> bf16 convert, both inputs in one dispatch ----------
__global__ __launch_bounds__(256) void cvt2_kernel(const float4* __restrict__ inq,
                                                   const float4* __restrict__ inkv,
                                                   ushort4* __restrict__ outq,
                                                   ushort4* __restrict__ outkv, int n4) {
  const float4* in = blockIdx.z ? inkv : inq;
  ushort4* out = blockIdx.z ? outkv : outq;
  int i = blockIdx.x * 256 + threadIdx.x;
  if (i < n4) {
    float4 v = in[i];
    ushort4 r;
    r.x = f2bf(v.x); r.y = f2bf(v.y); r.z = f2bf(v.z); r.w = f2bf(v.w);
    out[i] = r;
  }
}

// ---------- sin/cos table ----------
__global__ __launch_bounds__(256) void sincos_kernel(float2* __restrict__ sc) {
  int i = blockIdx.x * 256 + threadIdx.x;
  int s = i >> 6, j = i & 63;
  float inv_ts = 1.0f / powf(10000.0f, (float)j * (1.0f / 64.0f));
  float ang = (float)s * inv_ts;
  sc[i] = make_float2(sinf(ang), cosf(ang));
}

// ---------- RoPE (+scale), z=0: Q (scaled by 1/sqrt(HD)*log2e), z=1: K ----------
__global__ __launch_bounds__(256) void rope8_kernel(const unsigned short* __restrict__ XQ,
                                                    const unsigned short* __restrict__ XK,
                                                    const float2* __restrict__ sc,
                                                    unsigned short* __restrict__ outQ,
                                                    unsigned short* __restrict__ outK,
                                                    float qscale) {
  const unsigned short* X = blockIdx.z ? XK : XQ;
  unsigned short* out = blockIdx.z ? outK : outQ;
  float scale = blockIdx.z ? 1.0f : qscale;
  int i = blockIdx.x * 256 + threadIdx.x;   // [4096][16][8]
  int m = i >> 7;
  int r = i & 127;
  int h = r >> 3, jb = (r & 7) * 8;
  int s = m & (S_LEN - 1);
  size_t base = (size_t)m * DMODEL + h * HDIM + jb;
  int4 x1 = *(const int4*)(X + base);
  int4 x2 = *(const int4*)(X + base + 64);
  const float2* pp = sc + s * 64 + jb;
  int4 o1, o2;
  int* x1w = (int*)&x1; int* x2w = (int*)&x2;
  int* o1w = (int*)&o1; int* o2w = (int*)&o2;
#pragma unroll
  for (int w = 0; w < 4; w++) {
    float a_lo = bf2f((unsigned short)(x1w[w] & 0xffff));
    float a_hi = bf2f((unsigned short)((unsigned int)x1w[w] >> 16));
    float b_lo = bf2f((unsigned short)(x2w[w] & 0xffff));
    float b_hi = bf2f((unsigned short)((unsigned int)x2w[w] >> 16));
    float2 c0 = pp[w * 2], c1 = pp[w * 2 + 1];
    float r1l = (a_lo * c0.y - b_lo * c0.x) * scale;
    float r1h = (a_hi * c1.y - b_hi * c1.x) * scale;
    float r2l = (b_lo * c0.y + a_lo * c0.x) * scale;
    float r2h = (b_hi * c1.y + a_hi * c1.x) * scale;
    o1w[w] = (int)(cvt_pk_bf16(r1l, r1h));
    o2w[w] = (int)(cvt_pk_bf16(r2l, r2h));
  }
  *(int4*)(out + base) = o1;
  *(int4*)(out + base + 64) = o2;
}

// ---------- 2048x2048 weight transpose + convert, 4 weights ----------
__global__ __launch_bounds__(256) void wtrans4_kernel(const float* __restrict__ w0,
                                                      const float* __restrict__ w1,
                                                      const float* __restrict__ w2,
                                                      const float* __restrict__ w3,
                                                      unsigned short* __restrict__ outb) {
  __shared__ float tile[64][65];
  int z = blockIdx.z;
  const float* in = (z == 0) ? w0 : (z == 1) ? w1 : (z == 2) ? w2 : w3;
  unsigned short* out = outb + (size_t)z * DMODEL * DMODEL;
  int c0 = blockIdx.x * 64, r0 = blockIdx.y * 64;
  int tx = threadIdx.x & 63, ty = threadIdx.x >> 6;
#pragma unroll
  for (int i = 0; i < 16; i++) {
    int r = ty + i * 4;
    tile[r][tx] = in[(size_t)(r0 + r) * DMODEL + c0 + tx];
  }
  __syncthreads();
#pragma unroll
  for (int i = 0; i < 16; i++) {
    int c = ty + i * 4;
    out[(size_t)(c0 + c) * DMODEL + r0 + tx] = f2bf(tile[tx][c]);
  }
}

// ---------- V transpose: [B,S,H,HD] bf16 -> [B,H,HD,S] bf16 ----------
__global__ __launch_bounds__(256) void vtrans_kernel(const unsigned short* __restrict__ vf,
                                                     unsigned short* __restrict__ Vt) {
  __shared__ unsigned short tile[64][65];
  int z = blockIdx.z; int b = z >> 4, h = z & 15;
  const unsigned short* I = vf + (size_t)b * S_LEN * DMODEL + h * HDIM;
  unsigned short* O = Vt + (size_t)z * HDIM * S_LEN;
  int s0 = blockIdx.y * 64, f0 = blockIdx.x * 64;
  int tx = threadIdx.x & 63, ty = threadIdx.x >> 6;
#pragma unroll
  for (int i = 0; i < 16; i++) {
    int r = ty + i * 4;
    tile[r][tx] = I[(size_t)(s0 + r) * DMODEL + f0 + tx];
  }
  __syncthreads();
#pragma unroll
  for (int i = 0; i < 16; i++) {
    int c = ty + i * 4;
    O[(size_t)(f0 + c) * S_LEN + s0 + tx] = tile[tx][c];
  }
}

// ---------- 256x256 bf16 GEMM, octet pipeline, 1 barrier / K-tile ----------
__global__ __launch_bounds__(512, 1) void gemm256o_kernel(
    const unsigned short* __restrict__ Aq,
    const unsigned short* __restrict__ Akv,
    const unsigned short* __restrict__ W,    // [z][N][K]
    unsigned short* __restrict__ Cb) {       // [z][M][N] bf16
  constexpr int M = 4096, N = 2048, K = 2048, NT = K / 64;
  __shared__ char lds[131072];
  int wid = blockIdx.z * 128 + blockIdx.y * 8 + blockIdx.x;
  int nid = (wid & 7) * 32 + (wid >> 3);
  int z = nid >> 7;
  int rem = nid & 127;
  int bm = (rem >> 3) * 256, bn = (rem & 7) * 256;
  const unsigned short* A = (z == 0) ? Aq : Akv;
  const unsigned short* Bt = W + (size_t)z * N * K;

  int tid = threadIdx.x, wave = tid >> 6, lane = tid & 63;
  int lr = lane & 15, lq = lane >> 4;
  int wr = wave >> 2, wc = wave & 3;

  auto STAGE_P = [&](int t, int buf, int isB) {
    int k0 = t * 64;
    const unsigned short* src = isB ? Bt : A;
    int rbase = isB ? bn : bm;
    char* dst0 = lds + buf * 65536 + isB * 32768;
#pragma unroll
    for (int i = 0; i < 4; i++) {
      int o = i * 8192 + tid * 16;
      int row = o >> 7, colb = o & 127;
      int sc = colb ^ ((row & 7) << 4);
      __builtin_amdgcn_global_load_lds(
          (gas_cvp)(src + (size_t)(rbase + row) * K + k0 + (sc >> 1)),
          (las_vp)(dst0 + i * 8192 + wave * 1024), 16, 0, 0);
    }
  };
  auto LDA1 = [&](int buf, int m, int kk) -> bf16x8 {
    int row = wr * 128 + m * 16 + lr;
    return *(const bf16x8*)(lds + buf * 65536 + row * 128 +
                            (((kk * 4 + lq) ^ (row & 7)) << 4));
  };
  auto LDB1 = [&](int buf, int n, int kk) -> bf16x8 {
    int row = wc * 64 + n * 16 + lr;
    return *(const bf16x8*)(lds + buf * 65536 + 32768 + row * 128 +
                            (((kk * 4 + lq) ^ (row & 7)) << 4));
  };

  f32x4 acc[8][4] = {};
  bf16x8 aA[4][2], bB[4][2];

  auto OCT = [&](int P, int Q, int sb) {
#pragma unroll
    for (int kk = 0; kk < 2; kk++)
#pragma unroll
      for (int s = 0; s < 2; s++)
#pragma unroll
        for (int nn = 0; nn < 2; nn++)
          acc[2 * P + s][2 * Q + nn] = __builtin_amdgcn_mfma_f32_16x16x32_bf16(
              aA[sb + s][kk], bB[2 * Q + nn][kk], acc[2 * P + s][2 * Q + nn], 0, 0, 0);
  };
  auto RD_A2 = [&](int buf, int m0, int sb) {
#pragma unroll
    for (int kk = 0; kk < 2; kk++)
#pragma unroll
      for (int s = 0; s < 2; s++) aA[sb + s][kk] = LDA1(buf, m0 + s, kk);
  };
  auto RD_B2 = [&](int buf, int n0) {
#pragma unroll
    for (int kk = 0; kk < 2; kk++)
#pragma unroll
      for (int s = 0; s < 2; s++) bB[n0 + s][kk] = LDB1(buf, n0 + s, kk);
  };

  STAGE_P(0, 0, 0); STAGE_P(0, 0, 1);
  asm volatile("s_waitcnt vmcnt(0)" ::: "memory");
  __builtin_amdgcn_sched_barrier(0);

  for (int T = 0; T < NT; T++) {
    int c = T & 1, nc = c ^ 1;
    __builtin_amdgcn_s_barrier();
    if (T + 1 < NT) { STAGE_P(T + 1, nc, 0); STAGE_P(T + 1, nc, 1); }
    __builtin_amdgcn_sched_barrier(0);
    RD_A2(c, 0, 0);
    __builtin_amdgcn_sched_barrier(0);
    RD_B2(c, 0);
    __builtin_amdgcn_sched_barrier(0);
    RD_B2(c, 2);
    __builtin_amdgcn_sched_barrier(0);
    RD_A2(c, 2, 2);
    __builtin_amdgcn_sched_barrier(0);

    asm volatile("s_waitcnt lgkmcnt(8)" ::: "memory");
    __builtin_amdgcn_sched_barrier(0);
    __builtin_amdgcn_s_setprio(1);
    OCT(0, 0, 0);
    __builtin_amdgcn_s_setprio(0);
    asm volatile("s_waitcnt lgkmcnt(4)" ::: "memory");
    __builtin_amdgcn_sched_barrier(0);
    __builtin_amdgcn_s_setprio(1);
    OCT(0, 1, 0);
    __builtin_amdgcn_s_setprio(0);
    RD_A2(c, 4, 0);
    __builtin_amdgcn_sched_barrier(0);
    asm volatile("s_waitcnt lgkmcnt(4)" ::: "memory");
    __builtin_amdgcn_sched_barrier(0);
    __builtin_amdgcn_s_setprio(1);
    OCT(1, 0, 2); OCT(1, 1, 2);
    __builtin_amdgcn_s_setprio(0);
    RD_A2(c, 6, 2);
    __builtin_amdgcn_sched_barrier(0);
    asm volatile("s_waitcnt lgkmcnt(4)" ::: "memory");
    __builtin_amdgcn_sched_barrier(0);
    __builtin_amdgcn_s_setprio(1);
    OCT(2, 0, 0); OCT(2, 1, 0);
    __builtin_amdgcn_s_setprio(0);
    asm volatile("s_waitcnt lgkmcnt(0)" ::: "memory");
    __builtin_amdgcn_sched_barrier(0);
    __builtin_amdgcn_s_setprio(1);
    OCT(3, 0, 2); OCT(3, 1, 2);
    __builtin_amdgcn_s_setprio(0);
    if (T + 1 < NT) {
      asm volatile("s_waitcnt vmcnt(0)" ::: "memory");
      __builtin_amdgcn_sched_barrier(0);
    }
  }
  asm volatile("s_waitcnt vmcnt(0) lgkmcnt(0)" ::: "memory");

  unsigned short* C = Cb + (size_t)z * M * N;
#pragma unroll
  for (int m = 0; m < 8; m++)
#pragma unroll
    for (int n = 0; n < 4; n++) {
      int row0 = bm + wr * 128 + m * 16 + lq * 4;
      int col = bn + wc * 64 + n * 16 + lr;
#pragma unroll
      for (int r = 0; r < 4; r++)
        C[(size_t)(row0 + r) * N + col] = f2bf(acc[m][n][r]);
    }
}

// ---------- 256x128 bf16 GEMM, triple-buffer, 1 barrier / K-tile ----------
template <bool BF16OUT>
__global__ __launch_bounds__(512, 1) void gemmk_kernel(
    const unsigned short* __restrict__ Aq,
    const unsigned short* __restrict__ Akv,
    const unsigned short* __restrict__ W,   // [z][N][K]
    void* __restrict__ Cb) {                // [M][N]
  constexpr int M = 4096, N = 2048, K = 2048, NT = K / 64;
  __shared__ char lds[147456];
  int z = blockIdx.z;
  const unsigned short* A = (z == 0) ? Aq : Akv;
  const unsigned short* Bt = W + (size_t)z * N * K;

  int wid = blockIdx.y * 16 + blockIdx.x;
  int nid = (wid & 7) * 32 + (wid >> 3);
  int bn = (nid & 15) * 128, bm = (nid >> 4) * 256;

  int tid = threadIdx.x, wave = tid >> 6, lane = tid & 63;
  int lr = lane & 15, lq = lane >> 4;
  int wr = wave >> 1, wc = wave & 1;

  auto STAGE_U = [&](int t, int buf, int which) {
    int k0 = t * 64;
    const unsigned short* src = (which < 2) ? A : Bt;
    int rbase = (which < 2) ? (bm + which * 128) : bn;
    char* dst0 = lds + buf * 49152 + which * 16384;
#pragma unroll
    for (int i = 0; i < 2; i++) {
      int o = i * 8192 + wave * 1024 + lane * 16;
      int row = o >> 7, colb = o & 127;
      int sc = colb ^ ((row & 7) << 4);
      __builtin_amdgcn_global_load_lds(
          (gas_cvp)(src + (size_t)(rbase + row) * K + k0 + (sc >> 1)),
          (las_vp)(dst0 + i * 8192 + wave * 1024), 16, 0, 0);
    }
  };
  auto LDA = [&](int buf, int m, int kk) -> bf16x8 {
    int row = wr * 64 + m * 16 + lr;
    int half = row >> 7, r = row & 127;
    int byt = r * 128 + (((kk * 4 + lq) ^ (r & 7)) << 4);
    return *(const bf16x8*)(lds + buf * 49152 + half * 16384 + byt);
  };
  auto LDB = [&](int buf, int n, int kk) -> bf16x8 {
    int row = wc * 64 + n * 16 + lr;
    int byt = row * 128 + (((kk * 4 + lq) ^ (row & 7)) << 4);
    return *(const bf16x8*)(lds + buf * 49152 + 32768 + byt);
  };

  f32x4 acc[4][4] = {};
  bf16x8 aA[4][2], bB[4][2];

  auto QUAD = [&](int mg, int ng) {
#pragma unroll
    for (int kk = 0; kk < 2; kk++)
#pragma unroll
      for (int mm = 0; mm < 2; mm++)
#pragma unroll
        for (int nn = 0; nn < 2; nn++)
          acc[mg * 2 + mm][ng * 2 + nn] = __builtin_amdgcn_mfma_f32_16x16x32_bf16(
              aA[mg * 2 + mm][kk], bB[ng * 2 + nn][kk], acc[mg * 2 + mm][ng * 2 + nn], 0, 0, 0);
  };

  auto BODY = [&](int T, int cur, int dst, int mode) {
    __builtin_amdgcn_s_barrier();
    if (mode == 0) {
      STAGE_U(T + 2, dst, 0); STAGE_U(T + 2, dst, 1); STAGE_U(T + 2, dst, 2);
    }
    __builtin_amdgcn_sched_barrier(0);
#pragma unroll
    for (int kk = 0; kk < 2; kk++)
#pragma unroll
      for (int mm = 0; mm < 2; mm++) aA[mm][kk] = LDA(cur, mm, kk);
#pragma unroll
    for (int kk = 0; kk < 2; kk++)
#pragma unroll
      for (int nn = 0; nn < 2; nn++) bB[nn][kk] = LDB(cur, nn, kk);
    __builtin_amdgcn_sched_barrier(0);
#pragma unroll
    for (int kk = 0; kk < 2; kk++)
#pragma unroll
      for (int nn = 0; nn < 2; nn++) bB[2 + nn][kk] = LDB(cur, 2 + nn, kk);
    __builtin_amdgcn_sched_barrier(0);
#pragma unroll
    for (int kk = 0; kk < 2; kk++)
#pragma unroll
      for (int mm = 0; mm < 2; mm++) aA[2 + mm][kk] = LDA(cur, 2 + mm, kk);
    __builtin_amdgcn_sched_barrier(0);

    asm volatile("s_waitcnt lgkmcnt(8)" ::: "memory");
    __builtin_amdgcn_sched_barrier(0);
    __builtin_amdgcn_s_setprio(1);
    QUAD(0, 0);
    __builtin_amdgcn_s_setprio(0);
    asm volatile("s_waitcnt lgkmcnt(4)" ::: "memory");
    __builtin_amdgcn_sched_barrier(0);
    __builtin_amdgcn_s_setprio(1);
    QUAD(0, 1);
    __builtin_amdgcn_s_setprio(0);
    asm volatile("s_waitcnt lgkmcnt(0)" ::: "memory");
    __builtin_amdgcn_sched_barrier(0);
    __builtin_amdgcn_s_setprio(1);
    QUAD(1, 0); QUAD(1, 1);
    __builtin_amdgcn_s_setprio(0);
    if (mode == 0)      asm volatile("s_waitcnt vmcnt(6)" ::: "memory");
    else if (mode == 1) asm volatile("s_waitcnt vmcnt(0)" ::: "memory");
    __builtin_amdgcn_sched_barrier(0);
  };

  STAGE_U(0, 0, 0); STAGE_U(0, 0, 1); STAGE_U(0, 0, 2);
  STAGE_U(1, 1, 0); STAGE_U(1, 1, 1); STAGE_U(1, 1, 2);
  asm volatile("s_waitcnt vmcnt(6)" ::: "memory");
  __builtin_amdgcn_sched_barrier(0);

  int cur = 0;
  for (int T = 0; T < NT - 2; T++) {
    int dst = (cur == 0) ? 2 : cur - 1;
    BODY(T, cur, dst, 0);
    cur = (cur == 2) ? 0 : cur + 1;
  }
  BODY(NT - 2, cur, 0, 1);
  cur = (cur == 2) ? 0 : cur + 1;
  BODY(NT - 1, cur, 0, 2);
  asm volatile("s_waitcnt vmcnt(0) lgkmcnt(0)" ::: "memory");

#pragma unroll
  for (int m = 0; m < 4; m++)
#pragma unroll
    for (int n = 0; n < 4; n++) {
      int row0 = bm + wr * 64 + m * 16 + lq * 4;
      int col = bn + wc * 64 + n * 16 + lr;
      if (BF16OUT) {
        unsigned short* C = (unsigned short*)Cb;
#pragma unroll
        for (int r = 0; r < 4; r++)
          C[(size_t)(row0 + r) * N + col] = f2bf(acc[m][n][r]);
      } else {
        float* C = (float*)Cb;
#pragma unroll
        for (int r = 0; r < 4; r++)
          C[(size_t)(row0 + r) * N + col] = acc[m][n][r];
      }
    }
}

// ---------- causal flash attention: 1 q-tile/block, 8 waves x 16 rows ----------
// grid 512 = 2 blocks/CU (LDS 2x64KB, VGPR<=128 via launch_bounds(512,4)).
// hb = d&31 keeps same-(b,h) on one XCD; rank = d>>5 orders heavy tiles first;
// slot-paired blocks (d, d+256) have complementary qtiles (sum 34 iters).
__global__ __launch_bounds__(512, 4) void attn_kernel(const unsigned short* __restrict__ Qb,
                                                      const unsigned short* __restrict__ Kb,
                                                      const unsigned short* __restrict__ Vt,
                                                      unsigned short* __restrict__ ctx) {
  __shared__ char lds[65536];   // dbuf: [2][ K 16KB | V^T 16KB ]
  int d = blockIdx.x;
  int hb = d & 31;
  int rank = d >> 5;
  int qtile = (rank < 8) ? (15 - rank) : (rank - 8);
  int h = hb & 15, b = hb >> 4;

  int tid = threadIdx.x, wave = tid >> 6, lane = tid & 63;
  int lr = lane & 15, lq = lane >> 4;
  int qw = qtile * 128 + wave * 16;
  int nt = 2 * qtile + 2;

  const unsigned short* Qp = Qb + (size_t)b * S_LEN * DMODEL + (size_t)h * HDIM;
  const unsigned short* Kp = Kb + (size_t)b * S_LEN * DMODEL + (size_t)h * HDIM;
  const unsigned short* Vp = Vt + (size_t)(b * NH + h) * HDIM * S_LEN;

  bf16x8 qa[4];
#pragma unroll
  for (int kf = 0; kf < 4; kf++)
    qa[kf] = *(const bf16x8*)(Qp + (size_t)(qw + lr) * DMODEL + kf * 32 + lq * 8);

  f32x4 o[8] = {};
  float mrow = -1e30f;
  float lsum = 0.f;
  bool hi = (lane >= 32);
  bool odd = (lq & 1);

  auto STAGE = [&](int tt, int bsel) {
    int kk0 = tt * 64;
#pragma unroll
    for (int i = 0; i < 2; i++) {             // K tile [64][128] bf16, 16KB
      int o_ = wave * 2048 + i * 1024 + lane * 16;
      int row = o_ >> 8, colb = o_ & 255;
      int sc_ = colb ^ ((row & 7) << 4);
      __builtin_amdgcn_global_load_lds(
          (gas_cvp)(Kp + (size_t)(kk0 + row) * DMODEL + (sc_ >> 1)),
          (las_vp)(lds + bsel * 32768 + wave * 2048 + i * 1024), 16, 0, 0);
    }
#pragma unroll
    for (int i = 0; i < 2; i++) {             // V^T tile [128][64] bf16, 16KB
      int o_ = wave * 2048 + i * 1024 + lane * 16;
      int row = o_ >> 7, colb = o_ & 127;
      int sc_ = colb ^ ((row & 7) << 4);
      __builtin_amdgcn_global_load_lds(
          (gas_cvp)(Vp + (size_t)row * S_LEN + kk0 + (sc_ >> 1)),
          (las_vp)(lds + bsel * 32768 + 16384 + wave * 2048 + i * 1024), 16, 0, 0);
    }
  };

  STAGE(0, 0);
  __syncthreads();

  for (int t = 0; t < nt; t++) {
    int cur = t & 1;
    int k0 = t * 64;
    if (t + 1 < nt) STAGE(t + 1, cur ^ 1);

    bool active = (k0 <= qw + 15);
    if (active) {
      const char* kbb = lds + cur * 32768;
      f32x4 sf[4] = {};
#pragma unroll
      for (int kf = 0; kf < 4; kf++) {
        bf16x8 kbf[4];
#pragma unroll
        for (int nf = 0; nf < 4; nf++) {
          int row = nf * 16 + lr;
          int colb = kf * 64 + lq * 16;
          kbf[nf] = *(const bf16x8*)(kbb + row * 256 + (colb ^ ((row & 7) << 4)));
        }
#pragma unroll
        for (int nf = 0; nf < 4; nf++)
          sf[nf] = __builtin_amdgcn_mfma_f32_16x16x32_bf16(kbf[nf], qa[kf], sf[nf], 0, 0, 0);
      }

      // causal mask: k = k0 + nf*16 + lq*4 + r;  q = qw + lr
      if (k0 + 63 > qw) {
        int q = qw + lr;
#pragma unroll
        for (int nf = 0; nf < 4; nf++)
#pragma unroll
          for (int r = 0; r < 4; r++)
            if (k0 + nf * 16 + lq * 4 + r > q) sf[nf][r] = -1e30f;
      }

      float v = sf[0][0];
#pragma unroll
      for (int nf = 0; nf < 4; nf++)
#pragma unroll
        for (int r = 0; r < 4; r++) v = fmaxf(v, sf[nf][r]);
      v = fmaxf(v, __shfl_xor(v, 16));
      v = fmaxf(v, __shfl_xor(v, 32));
      bool need = (v > mrow + 8.f);
      if (__any(need)) {
        float mn = fmaxf(mrow, v);
        float al = exp2f(mrow - mn);
        mrow = mn;
        lsum *= al;
#pragma unroll
        for (int ff = 0; ff < 8; ff++) o[ff] *= al;
      }
      float rs = 0.f;
#pragma unroll
      for (int nf = 0; nf < 4; nf++)
#pragma unroll
        for (int r = 0; r < 4; r++) {
          float p = exp2f(sf[nf][r] - mrow);
          sf[nf][r] = p;
          rs += p;
        }
      rs += __shfl_xor(rs, 16);
      rs += __shfl_xor(rs, 32);
      lsum += rs;

      const char* vbb = lds + cur * 32768 + 16384;
#pragma unroll
      for (int c = 0; c < 2; c++) {
        unsigned int A0 = cvt_pk_bf16(sf[2 * c][0], sf[2 * c][1]);
        unsigned int A1 = cvt_pk_bf16(sf[2 * c][2], sf[2 * c][3]);
        unsigned int B0 = cvt_pk_bf16(sf[2 * c + 1][0], sf[2 * c + 1][1]);
        unsigned int B1 = cvt_pk_bf16(sf[2 * c + 1][2], sf[2 * c + 1][3]);
        unsigned int sA0 = (unsigned int)__shfl_xor((int)A0, 32);
        unsigned int sA1 = (unsigned int)__shfl_xor((int)A1, 32);
        unsigned int sB0 = (unsigned int)__shfl_xor((int)B0, 32);
        unsigned int sB1 = (unsigned int)__shfl_xor((int)B1, 32);
        unsigned int Y0f = hi ? sB0 : A0, Y0s = hi ? B0 : sA0;
        unsigned int Y1f = hi ? sB1 : A1, Y1s = hi ? B1 : sA1;
        unsigned int z0 = odd ? Y0f : Y0s, z1 = odd ? Y1f : Y1s;
        unsigned int w0 = (unsigned int)__shfl_xor((int)z0, 16);
        unsigned int w1 = (unsigned int)__shfl_xor((int)z1, 16);
        int4 fr;
        fr.x = (int)(odd ? w0 : Y0f);
        fr.y = (int)(odd ? w1 : Y1f);
        fr.z = (int)(odd ? Y0s : w0);
        fr.w = (int)(odd ? Y1s : w1);
        bf16x8 pfrag = __builtin_bit_cast(bf16x8, fr);
#pragma unroll
        for (int ff = 0; ff < 8; ff++) {
          int row = ff * 16 + lr;
          int colb = c * 64 + lq * 16;
          bf16x8 vb = *(const bf16x8*)(vbb + row * 128 + (colb ^ ((row & 7) << 4)));
          o[ff] = __builtin_amdgcn_mfma_f32_16x16x32_bf16(vb, pfrag, o[ff], 0, 0, 0);
        }
      }
    }

    __syncthreads();
  }

  float inv = 1.0f / lsum;
  size_t rb = ((size_t)b * S_LEN + qw + lr) * DMODEL + h * HDIM;
#pragma unroll
  for (int ff = 0; ff < 8; ff++) {
    unsigned int u0 = cvt_pk_bf16(o[ff][0] * inv, o[ff][1] * inv);
    unsigned int u1 = cvt_pk_bf16(o[ff][2] * inv, o[ff][3] * inv);
    *(uint2*)(ctx + rb + ff * 16 + lq * 4) = make_uint2(u0, u1);
  }
}

extern "C" void kernel_launch(void* const* d_in, const int* in_sizes, int n_in,
                              void* d_out, int out_size, void* d_ws, size_t ws_size,
                              hipStream_t stream) {
  const float* inq  = (const float*)d_in[0];
  const float* inkv = (const float*)d_in[1];
  const float* wq   = (const float*)d_in[2];
  const float* wk   = (const float*)d_in[3];
  const float* wv   = (const float*)d_in[4];
  const float* wo   = (const float*)d_in[5];
  float* out = (float*)d_out;

  char* ws = (char*)d_ws;
  const size_t MB = 1ull << 20;
  unsigned short* xq  = (unsigned short*)(ws);             // 16 MB (reused as Qb)
  unsigned short* xkv = (unsigned short*)(ws + 16 * MB);   // 16 MB (reused as Kb)
  unsigned short* wqt = (unsigned short*)(ws + 32 * MB);   // 8 MB
  unsigned short* wvt = (unsigned short*)(ws + 48 * MB);   // 8 MB
  unsigned short* wot = (unsigned short*)(ws + 56 * MB);   // 8 MB (wqt..wot contiguous)
  float2* sc          = (float2*)(ws + 64 * MB);           // 1 MB
  unsigned short* projb = (unsigned short*)(ws + 66 * MB); // 48 MB (Q,K,V bf16)
  unsigned short* Vt   = (unsigned short*)(ws + 114 * MB); // 16 MB
  unsigned short* ctxb = (unsigned short*)(ws + 130 * MB); // 16 MB
  unsigned short* Qb = xq;    // xq dead after proj GEMMs
  unsigned short* Kb = xkv;   // xkv dead after proj GEMMs

  const int n4 = (2 * S_LEN * DMODEL) / 4;
  cvt2_kernel<<<dim3(n4 / 256, 1, 2), 256, 0, stream>>>(
      (const float4*)inq, (const float4*)inkv, (ushort4*)xq, (ushort4*)xkv, n4);

  wtrans4_kernel<<<dim3(32, 32, 4), 256, 0, stream>>>(wq, wk, wv, wo, wqt);

  sincos_kernel<<<(S_LEN * 64) / 256, 256, 0, stream>>>(sc);

  // 1/sqrt(128) * log2(e): scores computed directly in log2 domain
  const float qscale = 0.12751743249052045f;
  unsigned short* projQ = projb;
  unsigned short* projK = projb + (size_t)4096 * 2048;
  unsigned short* projV = projb + (size_t)2 * 4096 * 2048;

  // Q,K projections: 256 blocks of 256x256 = 1 exact round
  gemm256o_kernel<<<dim3(8, 16, 2), 512, 0, stream>>>(xq, xkv, wqt, projb);
  // V projection: 256 blocks of 256x128 = 1 exact round
  gemmk_kernel<true><<<dim3(16, 16, 1), 512, 0, stream>>>(xkv, xkv, wvt, (void*)projV);

  rope8_kernel<<<dim3(2048, 1, 2), 256, 0, stream>>>(projQ, projK, sc, Qb, Kb, qscale);
  vtrans_kernel<<<dim3(2, 32, 32), 256, 0, stream>>>(projV, Vt);

  attn_kernel<<<512, 512, 0, stream>>>(Qb, Kb, Vt, ctxb);

  // output projection: 256 blocks = 1 exact round
  gemmk_kernel<false><<<dim3(16, 16, 1), 512, 0, stream>>>(ctxb, ctxb, wot, (void*)out);
}